// Round 17
// baseline (153.703 us; speedup 1.0000x reference)
//
#include <hip/hip_runtime.h>
#include <hip/hip_bf16.h>
#include <stdint.h>

#define CONF_T 0.05f
#define KSEL 1000
#define CAND_CAP 2048
#define ROWS 128
#define T1 256
#define SH_A 21          // pass-A window: bits[31:21] (11 bits, 2048 bins)
#define SH_B 10          // pass-B window: bits[20:10] (11 bits, 2048 bins)
#define NCH 12           // chunks per batch for grid-parallel mid kernels

// ---------------- Kernel 1: LDS-staged argmax + fused pass-A histogram ----------------
__global__ __launch_bounds__(T1) void score_argmax_hist_kernel(
    const float* __restrict__ probs, float* __restrict__ sc, int* __restrict__ cls,
    uint32_t* __restrict__ histA, int total, int N)
{
    __shared__ float tile[ROWS * 81];
    __shared__ uint32_t lh[2048];        // packed dual-batch: lo16 = b0, hi16 = b0+1
    const int r0  = blockIdx.x * ROWS;
    const int tid = threadIdx.x;
    const int rows_here = min(ROWS, total - r0);
    const int b0 = r0 / N;

    for (int i = tid; i < 2048; i += T1) lh[i] = 0u;

    const float4* src = reinterpret_cast<const float4*>(probs + (size_t)r0 * 80);
    const int nf4 = rows_here * 20;
    for (int f = tid; f < nf4; f += T1) {
        float4 v = src[f];
        int fo  = f * 4;
        int row = fo / 80;
        int col = fo - row * 80;
        float* dst = &tile[row * 81 + col];
        dst[0] = v.x; dst[1] = v.y; dst[2] = v.z; dst[3] = v.w;
    }
    __syncthreads();

    if (tid < rows_here) {
        const float* row = &tile[tid * 81];
        float best = row[0]; int bc = 0;
        #pragma unroll
        for (int j = 1; j < 80; ++j) {
            float v = row[j];
            if (v > best) { best = v; bc = j; }   // first-max-wins
        }
        const int gr = r0 + tid;
        sc[gr]  = best;
        cls[gr] = bc;
        const int sel = (gr / N) - b0;            // 0 or 1
        atomicAdd(&lh[__float_as_uint(best) >> SH_A], 1u << (16 * sel));
    }
    __syncthreads();

    for (int i = tid; i < 2048; i += T1) {
        uint32_t v = lh[i];
        if (v & 0xFFFFu) atomicAdd(&histA[(size_t)b0 * 2048 + i], v & 0xFFFFu);
        uint32_t hi = v >> 16;
        if (hi)          atomicAdd(&histA[(size_t)(b0 + 1) * 2048 + i], hi);
    }
}

// ---- wave-parallel crossing over 2048 LDS bins: find bin v (desc) where cumulative
// from top crosses rem; res = {v, rem_in_bin}. Uses wave 0 only; ~0.3us.
__device__ __forceinline__ void crossing2048(
    const uint32_t* __restrict__ hh, uint32_t rem, volatile uint32_t* __restrict__ res)
{
    __syncthreads();                       // hh fully populated
    if (threadIdx.x < 64) {
        const int lane = threadIdx.x;
        uint32_t s = 0;
        #pragma unroll 8
        for (int j = 0; j < 32; ++j) s += hh[lane * 32 + j];
        uint32_t suf = s;                  // suffix sum over lanes: suf[l] = sum_{m>=l} s[m]
        #pragma unroll
        for (int off = 1; off < 64; off <<= 1) {
            uint32_t t = __shfl_down(suf, off);
            if (lane + off < 64) suf += t;
        }
        unsigned long long m = __ballot(suf >= rem);
        int L = (m == 0) ? 0 : (63 - __clzll(m));        // highest lane with suf >= rem
        uint32_t cum_above = (L < 63) ? __shfl(suf, L + 1) : 0u;

        uint32_t binv = (lane < 32) ? hh[L * 32 + lane] : 0u;
        uint32_t suf2 = binv;
        #pragma unroll
        for (int off = 1; off < 32; off <<= 1) {
            uint32_t t = __shfl_down(suf2, off);
            if (lane + off < 32) suf2 += t;
        }
        unsigned long long m2 = __ballot(lane < 32 && (cum_above + suf2) >= rem);
        int j = (m2 == 0) ? 0 : (63 - __clzll(m2));
        uint32_t above2 = cum_above + ((j < 31) ? __shfl(suf2, j + 1) : 0u);
        if (lane == 0) {
            res[0] = (uint32_t)(L * 32 + j);
            res[1] = rem - above2;
        }
    }
    __syncthreads();
}

// ---------------- Kernel 2: grid-parallel pass-B histogram ----------------
__global__ __launch_bounds__(256) void histB_kernel(
    const float* __restrict__ scores, const uint32_t* __restrict__ histA,
    uint32_t* __restrict__ histB, int N)
{
    const int b  = blockIdx.x / NCH;
    const int ch = blockIdx.x % NCH;
    const int tid = threadIdx.x;
    __shared__ uint32_t hh[2048];
    __shared__ uint32_t res[2];

    for (int i = tid; i < 2048; i += 256) hh[i] = histA[(size_t)b * 2048 + i];
    crossing2048(hh, KSEL, res);
    const uint32_t vA = res[0];

    for (int i = tid; i < 2048; i += 256) hh[i] = 0u;
    __syncthreads();

    const float4* s4 = reinterpret_cast<const float4*>(scores + (size_t)b * N);
    const int n4  = N >> 2;
    const int cf4 = (n4 + NCH - 1) / NCH;
    const int fb  = ch * cf4, fe = min(fb + cf4, n4);
    for (int f = fb + tid; f < fe; f += 256) {
        float4 v = s4[f];
        #pragma unroll
        for (int j = 0; j < 4; ++j) {
            uint32_t bits = __float_as_uint(j==0 ? v.x : j==1 ? v.y : j==2 ? v.z : v.w);
            if ((bits >> SH_A) == vA)
                atomicAdd(&hh[(bits >> SH_B) & 0x7FFu], 1u);
        }
    }
    __syncthreads();
    for (int i = tid; i < 2048; i += 256)
        if (hh[i]) atomicAdd(&histB[(size_t)b * 2048 + i], hh[i]);
}

// ---------------- Kernel 3: grid-parallel gather of candidates ----------------
__global__ __launch_bounds__(256) void gather_kernel(
    const float* __restrict__ scores, const uint32_t* __restrict__ histA,
    const uint32_t* __restrict__ histB, uint32_t* __restrict__ gcnt,
    uint64_t* __restrict__ gcand, int N)
{
    const int b  = blockIdx.x / NCH;
    const int ch = blockIdx.x % NCH;
    const int tid = threadIdx.x;
    __shared__ uint32_t hh[2048];
    __shared__ uint32_t res[2];

    for (int i = tid; i < 2048; i += 256) hh[i] = histA[(size_t)b * 2048 + i];
    crossing2048(hh, KSEL, res);
    const uint32_t vA = res[0], remA = res[1];

    for (int i = tid; i < 2048; i += 256) hh[i] = histB[(size_t)b * 2048 + i];
    crossing2048(hh, remA, res);
    const uint32_t t_lo = (vA << SH_A) | (res[0] << SH_B);

    const float4* s4 = reinterpret_cast<const float4*>(scores + (size_t)b * N);
    const int n4  = N >> 2;
    const int cf4 = (n4 + NCH - 1) / NCH;
    const int fb  = ch * cf4, fe = min(fb + cf4, n4);
    for (int f = fb + tid; f < fe; f += 256) {
        float4 v = s4[f];
        #pragma unroll
        for (int j = 0; j < 4; ++j) {
            uint32_t bits = __float_as_uint(j==0 ? v.x : j==1 ? v.y : j==2 ? v.z : v.w);
            if (bits >= t_lo) {
                uint32_t pos = atomicAdd(&gcnt[b], 1u);
                if (pos < CAND_CAP)
                    gcand[(size_t)b * CAND_CAP + pos] =
                        ((uint64_t)(~bits) << 32) | (uint64_t)(uint32_t)(4*f + j);  // ties: ASC idx
            }
        }
    }
}

// ---------------- Kernel 4: rank + decode + write (candidates only) ----------------
__global__ __launch_bounds__(1024) void final_select_kernel(
    const uint32_t* __restrict__ gcnt, const uint64_t* __restrict__ gcand,
    const int* __restrict__ cls_ws,
    const float* __restrict__ anchors, const float* __restrict__ offsets,
    const float* __restrict__ window, float* __restrict__ out,
    int N, int B)
{
    const int b   = blockIdx.x;
    const int tid = threadIdx.x;
    __shared__ uint64_t cand[CAND_CAP];

    uint32_t G = gcnt[b];
    if (G > CAND_CAP) G = CAND_CAP;
    for (uint32_t i = tid; i < G; i += 1024) cand[i] = gcand[(size_t)b * CAND_CAP + i];
    __syncthreads();

    const float wy1 = window[0], wx1 = window[1], wy2 = window[2], wx2 = window[3];
    const int BK = B * KSEL;
    float* o_ai = out;             // [B,K,2] (b, idx)
    float* o_bx = out + 2 * BK;    // [B,K,4]
    float* o_cl = out + 6 * BK;
    float* o_sc = out + 7 * BK;
    float* o_vd = out + 8 * BK;

    for (uint32_t c = tid; c < G; c += 1024) {
        const uint64_t kc = cand[c];
        uint32_t r = 0;
        for (uint32_t j = 0; j < G; ++j) r += (cand[j] < kc) ? 1u : 0u;
        if (r >= KSEL) continue;

        uint32_t idx   = (uint32_t)kc;
        uint32_t sbits = ~(uint32_t)(kc >> 32);
        float score    = __uint_as_float(sbits);

        size_t base = (size_t)b * N + idx;
        const float4 a = *reinterpret_cast<const float4*>(anchors + base * 4);
        const float4 o = *reinterpret_cast<const float4*>(offsets + base * 4);

        float h  = a.z - a.x;
        float w  = a.w - a.y;
        float cy = a.x + 0.5f * h + o.x * h;
        float cx = a.y + 0.5f * w + o.y * w;
        float hh2 = h * expf(o.z);
        float ww  = w * expf(o.w);
        float y1 = fminf(fmaxf(cy - 0.5f * hh2, wy1), wy2);
        float x1 = fminf(fmaxf(cx - 0.5f * ww,  wx1), wx2);
        float y2 = fminf(fmaxf(cy + 0.5f * hh2, wy1), wy2);
        float x2 = fminf(fmaxf(cx + 0.5f * ww,  wx1), wx2);

        int ok = b * KSEL + (int)r;
        o_ai[ok*2 + 0] = (float)b;
        o_ai[ok*2 + 1] = (float)idx;
        o_bx[ok*4 + 0] = y1;
        o_bx[ok*4 + 1] = x1;
        o_bx[ok*4 + 2] = y2;
        o_bx[ok*4 + 3] = x2;
        o_cl[ok] = (float)cls_ws[base];
        o_sc[ok] = score;
        o_vd[ok] = (score > CONF_T) ? 1.0f : 0.0f;
    }
}

extern "C" void kernel_launch(void* const* d_in, const int* in_sizes, int n_in,
                              void* d_out, int out_size, void* d_ws, size_t ws_size,
                              hipStream_t stream)
{
    const float* anchors = (const float*)d_in[0];
    const float* probs   = (const float*)d_in[1];
    const float* offsets = (const float*)d_in[2];
    const float* window  = (const float*)d_in[3];

    const int B = out_size / (9 * KSEL);
    const int N = in_sizes[0] / (B * 4);
    const int total = B * N;

    // ws layout (8-aligned first): sc | cls | gcand | histA | histB | gcnt
    char* p = (char*)d_ws;
    float*    sc    = (float*)p;                        p += (size_t)total * 4;
    int*      cls   = (int*)p;                          p += (size_t)total * 4;
    uint64_t* gcand = (uint64_t*)p;                     p += (size_t)B * CAND_CAP * 8;
    uint32_t* histA = (uint32_t*)p;                     p += (size_t)B * 2048 * 4;
    uint32_t* histB = (uint32_t*)p;                     p += (size_t)B * 2048 * 4;
    uint32_t* gcnt  = (uint32_t*)p;

    // zero histA | histB | gcnt (contiguous)
    hipMemsetAsync(histA, 0, (size_t)B * (2048 * 2 + 1) * sizeof(uint32_t), stream);

    hipLaunchKernelGGL(score_argmax_hist_kernel,
                       dim3((total + ROWS - 1) / ROWS), dim3(T1), 0, stream,
                       probs, sc, cls, histA, total, N);

    hipLaunchKernelGGL(histB_kernel, dim3(B * NCH), dim3(256), 0, stream,
                       sc, histA, histB, N);

    hipLaunchKernelGGL(gather_kernel, dim3(B * NCH), dim3(256), 0, stream,
                       sc, histA, histB, gcnt, gcand, N);

    hipLaunchKernelGGL(final_select_kernel, dim3(B), dim3(1024), 0, stream,
                       gcnt, gcand, cls, anchors, offsets, window,
                       (float*)d_out, N, B);
}